// Round 8
// baseline (316.740 us; speedup 1.0000x reference)
//
#include <hip/hip_runtime.h>

#define NN 50000
#define NE 800000
#define NG 128
#define DIM 128
#define CO 10
#define CAP 64        // ELL row capacity; Poisson(16) tail beyond 64 is ~1e-20
#define NB 2048       // pool stage-1 blocks

// bucketed ELL build
#define BKT_SHIFT 7   // 128 nodes per bucket
#define BKT_NODES 128
#define NBKT 391      // ceil(50000/128)
#define NSEG 8        // per-bucket segments, selected by blockIdx&7 (~XCD)
#define SEGCAP 448    // mean 256/segment, 448 is +12 sigma

typedef unsigned long long ull;
typedef unsigned short ushort;
typedef unsigned int uint;
typedef __attribute__((ext_vector_type(8))) short short8;   // 8 bf16 (4 VGPRs)
typedef __attribute__((ext_vector_type(4))) float floatx4;

static __device__ __forceinline__ ushort f2bf(float f) {
    uint u = __float_as_uint(f);
    uint r = (u + 0x7FFF + ((u >> 16) & 1)) >> 16;   // RNE
    return (ushort)r;
}
#define EWS (1.0f / 65535.0f)
#define DGS (1.0f / 65536.0f)   // deg fixed-point scale (16.16)

// ---- phase A: bucket scatter ----
// rec64 = fp32(w) << 32 | dst_off7 << 16 | src16. Appends to segment (bucket, blockIdx&7):
// with round-robin block->XCD dispatch each segment is written by one XCD only, and
// positions are dense-sequential -> lines fill completely in ONE L2 and write back once.
// Old k_ell: 48MB of cross-XCD dirty-line ping-pong (measured r3). This: ~6.4MB.
__global__ void k_bucket(const int* __restrict__ src, const int* __restrict__ dst,
                         const float* __restrict__ ew, uint* __restrict__ bcnt,
                         ull* __restrict__ bkt) {
    int e = blockIdx.x * blockDim.x + threadIdx.x;
    if (e >= NE) return;
    int d = dst[e], s = src[e];
    float w = ew[e];
    int b = d >> BKT_SHIFT;
    int sb = b * NSEG + (blockIdx.x & 7);
    uint pos = atomicAdd(&bcnt[sb * 16], 1u);     // counters padded to 64B lines
    if (pos < SEGCAP) {
        ull rec = ((ull)__float_as_uint(w) << 32)
                | ((uint)(d & (BKT_NODES - 1)) << 16) | (uint)s;
        bkt[(size_t)sb * SEGCAP + pos] = rec;
    }
}

// ---- phase B: one block per bucket; build 128 ELL rows + cnt/deg in LDS, ----
// ---- then stream out densely. No global atomics; combo fully written here. ----
__global__ __launch_bounds__(256) void k_ellbuild(const uint* __restrict__ bcnt,
                                                  const ull* __restrict__ bkt,
                                                  ull* __restrict__ combo,
                                                  uint* __restrict__ ell) {
    __shared__ uint  lell[BKT_NODES * CAP];   // 32 KB
    __shared__ uint  lcnt[BKT_NODES];
    __shared__ float ldeg[BKT_NODES];
    int b = blockIdx.x, tid = threadIdx.x;
    for (int i = tid; i < BKT_NODES; i += 256) { lcnt[i] = 0; ldeg[i] = 0.0f; }
    __syncthreads();
    for (int seg = 0; seg < NSEG; seg++) {
        int sb = b * NSEG + seg;
        uint n = min(bcnt[sb * 16], (uint)SEGCAP);
        const ull* base = &bkt[(size_t)sb * SEGCAP];
        for (uint r = tid; r < n; r += 256) {
            ull rec = base[r];
            uint lo = (uint)rec;
            float w = __uint_as_float((uint)(rec >> 32));
            uint doff = (lo >> 16) & 0xffu;
            uint s = lo & 0xffffu;
            uint slot = atomicAdd(&lcnt[doff], 1u);
            atomicAdd(&ldeg[doff], w);
            if (slot < CAP) {
                uint w16 = (uint)__float2uint_rn(w * 65535.0f);
                lell[doff * CAP + slot] = (w16 << 16) | s;
            }
        }
    }
    __syncthreads();
    int node0 = b * BKT_NODES;
    for (int i = tid; i < BKT_NODES; i += 256) {
        int node = node0 + i;
        if (node < NN) {
            uint dfix = (uint)__float2uint_rn(ldeg[i] * 65536.0f);
            combo[node] = ((ull)dfix << 32) | (ull)lcnt[i];
        }
    }
    int nvalid = min(NN - node0, BKT_NODES);
    int nvec = nvalid * CAP / 4;               // uint4 count
    uint4* gdst = (uint4*)&ell[(size_t)node0 * CAP];
    const uint4* lsrc = (const uint4*)lell;
    for (int i = tid; i < nvec; i += 256) gdst[i] = lsrc[i];   // dense coalesced
}

// ---- W prep: Wt[n][k] = bf16(W[k][n]), both 128x128 weights in one launch ----
__global__ void k_prepw(const float* __restrict__ W1, const float* __restrict__ W2,
                        ushort* __restrict__ wt1, ushort* __restrict__ wt2) {
    int b = blockIdx.x;
    const float* W = (b < 64) ? W1 : W2;
    ushort* Wt = (b < 64) ? wt1 : wt2;
    int i = (b & 63) * 256 + threadIdx.x;   // 16384 per weight
    int k = i >> 7, n = i & 127;
    Wt[n * 128 + k] = f2bf(W[i]);
}

static __device__ __forceinline__ float combo_dinv(ull cb) {
    return rsqrtf(1.0f + (float)(uint)(cb >> 32) * DGS);
}

// ---- MFMA GEMM: C[M x 128](bf16) = dinv ⊙ (A[M x 128] @ W) ; A fp32 or bf16 ----
__global__ __launch_bounds__(256) void k_gemm_mfma(const void* __restrict__ Ain, int abf,
                                                   const ushort* __restrict__ Wt,
                                                   const ull* __restrict__ combo,
                                                   ushort* __restrict__ C, int M) {
    int wave = threadIdx.x >> 6;
    int lane = threadIdx.x & 63;
    int quad = lane >> 4;
    int mcol = lane & 15;
    int r0 = blockIdx.x * 64 + wave * 16;
    int arow = r0 + mcol;
    if (arow >= M) arow = M - 1;
    floatx4 acc[8];
#pragma unroll
    for (int t = 0; t < 8; t++) acc[t] = (floatx4){0.0f, 0.0f, 0.0f, 0.0f};

    const ushort* Ab = (const ushort*)Ain;
    const float*  Af = (const float*)Ain;
#pragma unroll
    for (int kk = 0; kk < 4; kk++) {
        int koff = kk * 32 + quad * 8;
        short8 a;
        if (abf) {
            a = *(const short8*)&Ab[(size_t)arow * 128 + koff];
        } else {
            const float* ap = &Af[(size_t)arow * 128 + koff];
            float4 x0 = *(const float4*)ap;
            float4 x1 = *(const float4*)(ap + 4);
            union { short8 v; ushort u[8]; } ua;
            ua.u[0] = f2bf(x0.x); ua.u[1] = f2bf(x0.y); ua.u[2] = f2bf(x0.z); ua.u[3] = f2bf(x0.w);
            ua.u[4] = f2bf(x1.x); ua.u[5] = f2bf(x1.y); ua.u[6] = f2bf(x1.z); ua.u[7] = f2bf(x1.w);
            a = ua.v;
        }
#pragma unroll
        for (int t = 0; t < 8; t++) {
            short8 b = *(const short8*)&Wt[(size_t)(t * 16 + mcol) * 128 + koff];
            acc[t] = __builtin_amdgcn_mfma_f32_16x16x32_bf16(a, b, acc[t], 0, 0, 0);
        }
    }
#pragma unroll
    for (int reg = 0; reg < 4; reg++) {
        int row = r0 + quad * 4 + reg;
        if (row < M) {
            float di = combo_dinv(combo[row]);
            ushort* cp = &C[(size_t)row * 128];
#pragma unroll
            for (int t = 0; t < 8; t++) cp[t * 16 + mcol] = f2bf(di * acc[t][reg]);
        }
    }
}

// ---- GEMM3: z'[M x 10](fp32) = dinv ⊙ (A[M x 128](bf16) @ W3[128 x 10]) ----
__global__ __launch_bounds__(256) void k_gemm10(const ushort* __restrict__ A,
                                                const float* __restrict__ W3,
                                                const ull* __restrict__ combo,
                                                float* __restrict__ C3, int M) {
    __shared__ float Ws[1280];
    int tid = threadIdx.x;
    for (int i = tid; i < 1280; i += 256) Ws[i] = W3[i];
    __syncthreads();
    int col = tid & 15;
    int rloc = tid >> 4;
    int row = blockIdx.x * 16 + rloc;
    if (row >= M || col >= 10) return;
    ull cb = combo[row];
    const ushort* a = &A[(size_t)row * 128];
    float acc = 0.0f;
#pragma unroll
    for (int k = 0; k < 128; k += 4) {
        ushort4 av = *(const ushort4*)&a[k];
        acc += __uint_as_float((uint)av.x << 16) * Ws[(k + 0) * 10 + col];
        acc += __uint_as_float((uint)av.y << 16) * Ws[(k + 1) * 10 + col];
        acc += __uint_as_float((uint)av.z << 16) * Ws[(k + 2) * 10 + col];
        acc += __uint_as_float((uint)av.w << 16) * Ws[(k + 3) * 10 + col];
    }
    C3[(size_t)row * 10 + col] = combo_dinv(cb) * acc;
}

// ---- ELL gather, 4-rows-per-instruction layout ----
__global__ __launch_bounds__(256) void k_gather128(const ull* __restrict__ combo,
                                                   const uint* __restrict__ ell,
                                                   const ushort* __restrict__ h,
                                                   const float* __restrict__ b,
                                                   ushort* __restrict__ outp) {
    int node = blockIdx.x * 4 + (threadIdx.x >> 6);
    int lane = threadIdx.x & 63;
    if (node >= NN) return;
    ull cb = combo[node];                          // one 8B broadcast: cnt + deg
    int n = min((int)(uint)cb, 63);                // keep self-slot n within 64 lanes
    float dg = (float)(uint)(cb >> 32) * DGS;
    int ce; float we;
    if (lane < n) {
        uint rec = ell[(size_t)node * CAP + lane];
        ce = (int)(rec & 0xffffu);
        we = (float)(rec >> 16) * EWS;
    } else {
        ce = node;
        we = (lane == n) ? 1.0f : 0.0f;
    }
    int grp  = lane >> 4;     // row-group 0..3
    int col8 = lane & 15;     // 8-col slice
    float acc[8];
#pragma unroll
    for (int f = 0; f < 8; f++) acc[f] = 0.0f;
    int nb = (n + 4) >> 2;    // ceil((n+1)/4) batches, all full (padded)
    for (int bi = 0; bi < nb; bi++) {
        int idx = (bi << 2) | grp;
        int s = __shfl(ce, idx);
        float w = __shfl(we, idx);
        uint4 p = *(const uint4*)&h[(size_t)s * 128 + col8 * 8];
        acc[0] += w * __uint_as_float(p.x << 16);
        acc[1] += w * __uint_as_float(p.x & 0xffff0000u);
        acc[2] += w * __uint_as_float(p.y << 16);
        acc[3] += w * __uint_as_float(p.y & 0xffff0000u);
        acc[4] += w * __uint_as_float(p.z << 16);
        acc[5] += w * __uint_as_float(p.z & 0xffff0000u);
        acc[6] += w * __uint_as_float(p.w << 16);
        acc[7] += w * __uint_as_float(p.w & 0xffff0000u);
    }
#pragma unroll
    for (int f = 0; f < 8; f++) {
        acc[f] += __shfl_xor(acc[f], 16);
        acc[f] += __shfl_xor(acc[f], 32);
    }
    if (lane < 16) {
        float di = rsqrtf(1.0f + dg);
        union { ushort u[8]; uint4 v; } o;
#pragma unroll
        for (int f = 0; f < 8; f++) {
            float vv = fmaxf(di * acc[f] + b[col8 * 8 + f], 0.0f);
            o.u[f] = f2bf(vv);
        }
        *(uint4*)&outp[(size_t)node * 128 + col8 * 8] = o.v;
    }
}

// ---- pool stage 1: wave per node; agg3[d] = dinv_d*(sum ew*z'[s] + z'[d]); pool by graph ----
__global__ __launch_bounds__(256) void k_pool_node(const ull* __restrict__ combo,
                                                   const uint* __restrict__ ell,
                                                   const float* __restrict__ z,
                                                   const int* __restrict__ batch,
                                                   float* __restrict__ partial) {
    __shared__ float ls[NG * CO + NG];
    for (int i = threadIdx.x; i < NG * CO + NG; i += 256) ls[i] = 0.0f;
    __syncthreads();
    int lane = threadIdx.x & 63;
    int gwave = blockIdx.x * 4 + (threadIdx.x >> 6);
    for (int node = gwave; node < NN; node += NB * 4) {
        ull cb = combo[node];
        int n = min((int)(uint)cb, CAP);
        float w = 0.0f; int s = 0;
        if (lane < n) {
            uint rec = ell[(size_t)node * CAP + lane];
            s = (int)(rec & 0xffffu);
            w = (float)(rec >> 16) * EWS;
        } else if (lane == n) {
            s = node;
            w = 1.0f;                 // self term: z'[d]
        }
        const float* zp = &z[(size_t)s * 10];
        float v[10];
#pragma unroll
        for (int f = 0; f < 10; f++) v[f] = w * zp[f];
#pragma unroll
        for (int off = 32; off; off >>= 1) {
#pragma unroll
            for (int f = 0; f < 10; f++) v[f] += __shfl_down(v[f], off);
        }
        if (lane == 0) {
            int g = batch[node];
            float di = combo_dinv(cb);
            float* lp = &ls[g * 10];
#pragma unroll
            for (int f = 0; f < 10; f++) atomicAdd(&lp[f], di * v[f]);
            atomicAdd(&ls[NG * CO + g], 1.0f);
        }
    }
    __syncthreads();
    float* pb = &partial[(size_t)blockIdx.x * (NG * CO + NG)];
    for (int i = threadIdx.x; i < NG * CO + NG; i += 256) pb[i] = ls[i];
}

// ---- pool stage 2 + log_softmax: one block (256 thr) per graph ----
__global__ __launch_bounds__(256) void k_pool_final(const float* __restrict__ partial,
                                                    const float* __restrict__ b3,
                                                    float* __restrict__ out) {
    __shared__ float red[4][11];
    int g = blockIdx.x;
    int t = threadIdx.x;
    int lane = t & 63, wv = t >> 6;
    float v[10]; float c = 0.0f;
#pragma unroll
    for (int f = 0; f < 10; f++) v[f] = 0.0f;
    for (int b = t; b < NB; b += 256) {
        const float* pb = &partial[(size_t)b * (NG * CO + NG)];
#pragma unroll
        for (int f = 0; f < 10; f++) v[f] += pb[g * 10 + f];
        c += pb[NG * CO + g];
    }
#pragma unroll
    for (int off = 32; off; off >>= 1) {
#pragma unroll
        for (int f = 0; f < 10; f++) v[f] += __shfl_down(v[f], off);
        c += __shfl_down(c, off);
    }
    if (lane == 0) {
#pragma unroll
        for (int f = 0; f < 10; f++) red[wv][f] = v[f];
        red[wv][10] = c;
    }
    __syncthreads();
    if (t == 0) {
        float p[10], m = -1e30f;
        float cc = red[0][10] + red[1][10] + red[2][10] + red[3][10];
        cc = fmaxf(cc, 1.0f);
#pragma unroll
        for (int f = 0; f < 10; f++) {
            p[f] = (red[0][f] + red[1][f] + red[2][f] + red[3][f]) / cc + b3[f];
            m = fmaxf(m, p[f]);
        }
        float ssum = 0.0f;
#pragma unroll
        for (int f = 0; f < 10; f++) ssum += __expf(p[f] - m);
        float lse = m + __logf(ssum);
#pragma unroll
        for (int f = 0; f < 10; f++) out[g * 10 + f] = p[f] - lse;
    }
}

extern "C" void kernel_launch(void* const* d_in, const int* in_sizes, int n_in,
                              void* d_out, int out_size, void* d_ws, size_t ws_size,
                              hipStream_t stream) {
    const float* x     = (const float*)d_in[0];
    const int*   ei    = (const int*)d_in[1];     // [2, E]
    const float* ea    = (const float*)d_in[2];
    const int*   batch = (const int*)d_in[3];
    const float* W1    = (const float*)d_in[4];
    const float* b1    = (const float*)d_in[5];
    const float* W2    = (const float*)d_in[6];
    const float* b2    = (const float*)d_in[7];
    const float* W3    = (const float*)d_in[8];
    const float* b3    = (const float*)d_in[9];
    float* out = (float*)d_out;
    float* ws  = (float*)d_ws;

    const int* esrc = ei;
    const int* edst = ei + NE;

    // workspace layout (float offsets; all 16B aligned)
    ushort* hb      = (ushort*)ws;                 // N*128 bf16 = 3,200,000 floats
    ushort* gb      = (ushort*)(ws + 3200000);     // N*128 bf16 = 3,200,000 floats
    float*  z       = ws + 6400000;                // 500,000
    ull*    combo   = (ull*)(ws + 6900000);        // NN x u64 (cnt | deg16.16)
    uint*   ell     = (uint*)(ws + 7000000);       // NN*CAP u32 = 3,200,000
    ushort* wt1     = (ushort*)(ws + 10200000);    // 16384 ushorts (bf16 W1^T)
    ushort* wt2     = (ushort*)(ws + 10210000);    // 16384 ushorts (bf16 W2^T)
    float*  partial = (float*)hb;                  // NB*1408 floats, overlays hb (dead then)
    // bucket overlays (dead before their overwriters run):
    ull*    bkt     = (ull*)gb;                    // NBKT*NSEG*SEGCAP*8B = 11.2MB <= gb(12.8MB)
    uint*   bcnt    = (uint*)z;                    // NBKT*NSEG*16 uints = 200KB <= z(2MB)

    // --- ELL build: bucket scatter (XCD-segmented) -> LDS-local ELL assembly ---
    hipMemsetAsync(bcnt, 0, (size_t)NBKT * NSEG * 16 * sizeof(uint), stream);
    k_bucket<<<(NE + 255) / 256, 256, 0, stream>>>(esrc, edst, ea, bcnt, bkt);
    k_ellbuild<<<NBKT, 256, 0, stream>>>(bcnt, bkt, combo, ell);
    k_prepw<<<128, 256, 0, stream>>>(W1, W2, wt1, wt2);

    // --- layer 1: h' = dinv*(X@W1) (MFMA) ; gather -> gb (bf16) ---
    k_gemm_mfma<<<(NN + 63) / 64, 256, 0, stream>>>(x, 0, wt1, combo, hb, NN);
    k_gather128<<<(NN + 3) / 4, 256, 0, stream>>>(combo, ell, hb, b1, gb);

    // --- layer 2 ---
    k_gemm_mfma<<<(NN + 63) / 64, 256, 0, stream>>>(gb, 1, wt2, combo, hb, NN);
    k_gather128<<<(NN + 3) / 4, 256, 0, stream>>>(combo, ell, hb, b2, gb);

    // --- layer 3: z' = dinv*(gb@W3), pool over nodes ---
    k_gemm10<<<(NN + 15) / 16, 256, 0, stream>>>(gb, W3, combo, z, NN);
    k_pool_node<<<NB, 256, 0, stream>>>(combo, ell, z, batch, partial);
    k_pool_final<<<NG, 256, 0, stream>>>(partial, b3, out);
}

// Round 10
// 296.888 us; speedup vs baseline: 1.0669x; 1.0669x over previous
//
#include <hip/hip_runtime.h>

#define NN 50000
#define NE 800000
#define NG 128
#define DIM 128
#define CO 10
#define CAP 64        // ELL row capacity; Poisson(16) tail beyond 64 is ~1e-20
#define NB 2048       // pool stage-1 blocks

// bucketed ELL build
#define BKT_SHIFT 7   // 128 nodes per bucket
#define BKT_NODES 128
#define NBKT 391      // ceil(50000/128)
#define NSEG 8        // per-bucket segments, selected by blockIdx&7 (~XCD)
#define SEGCAP 448    // mean 256/segment, 448 is +12 sigma

typedef unsigned long long ull;
typedef unsigned short ushort;
typedef unsigned int uint;
typedef __attribute__((ext_vector_type(8))) short short8;   // 8 bf16 (4 VGPRs)
typedef __attribute__((ext_vector_type(4))) float floatx4;

static __device__ __forceinline__ ushort f2bf(float f) {
    uint u = __float_as_uint(f);
    uint r = (u + 0x7FFF + ((u >> 16) & 1)) >> 16;   // RNE
    return (ushort)r;
}
#define EWS (1.0f / 65535.0f)
#define DGS (1.0f / 65536.0f)   // deg fixed-point scale (16.16)

// ---- phase A: bucket scatter ----
// rec64 = fp32(w) << 32 | dst_off7 << 16 | src16. Appends to segment (bucket, blockIdx&7):
// with round-robin block->XCD dispatch each segment is written by one XCD only, and
// positions are dense-sequential -> lines fill completely in ONE L2 and write back once.
// Old k_ell: 48MB cross-XCD dirty-line ping-pong, 55us (r3). r8: gone from top-5. WIN.
__global__ void k_bucket(const int* __restrict__ src, const int* __restrict__ dst,
                         const float* __restrict__ ew, uint* __restrict__ bcnt,
                         ull* __restrict__ bkt) {
    int e = blockIdx.x * blockDim.x + threadIdx.x;
    if (e >= NE) return;
    int d = dst[e], s = src[e];
    float w = ew[e];
    int b = d >> BKT_SHIFT;
    int sb = b * NSEG + (blockIdx.x & 7);
    uint pos = atomicAdd(&bcnt[sb * 16], 1u);     // counters padded to 64B lines
    if (pos < SEGCAP) {
        ull rec = ((ull)__float_as_uint(w) << 32)
                | ((uint)(d & (BKT_NODES - 1)) << 16) | (uint)s;
        bkt[(size_t)sb * SEGCAP + pos] = rec;
    }
}

// ---- phase B: one block per bucket; build 128 ELL rows + cnt/deg in LDS, ----
// ---- then stream out densely. No global atomics; combo fully written here. ----
__global__ __launch_bounds__(256) void k_ellbuild(const uint* __restrict__ bcnt,
                                                  const ull* __restrict__ bkt,
                                                  ull* __restrict__ combo,
                                                  uint* __restrict__ ell) {
    __shared__ uint  lell[BKT_NODES * CAP];   // 32 KB
    __shared__ uint  lcnt[BKT_NODES];
    __shared__ float ldeg[BKT_NODES];
    int b = blockIdx.x, tid = threadIdx.x;
    for (int i = tid; i < BKT_NODES; i += 256) { lcnt[i] = 0; ldeg[i] = 0.0f; }
    __syncthreads();
    for (int seg = 0; seg < NSEG; seg++) {
        int sb = b * NSEG + seg;
        uint n = min(bcnt[sb * 16], (uint)SEGCAP);
        const ull* base = &bkt[(size_t)sb * SEGCAP];
        for (uint r = tid; r < n; r += 256) {
            ull rec = base[r];
            uint lo = (uint)rec;
            float w = __uint_as_float((uint)(rec >> 32));
            uint doff = (lo >> 16) & 0xffu;
            uint s = lo & 0xffffu;
            uint slot = atomicAdd(&lcnt[doff], 1u);
            atomicAdd(&ldeg[doff], w);
            if (slot < CAP) {
                uint w16 = (uint)__float2uint_rn(w * 65535.0f);
                lell[doff * CAP + slot] = (w16 << 16) | s;
            }
        }
    }
    __syncthreads();
    int node0 = b * BKT_NODES;
    for (int i = tid; i < BKT_NODES; i += 256) {
        int node = node0 + i;
        if (node < NN) {
            uint dfix = (uint)__float2uint_rn(ldeg[i] * 65536.0f);
            combo[node] = ((ull)dfix << 32) | (ull)lcnt[i];
        }
    }
    int nvalid = min(NN - node0, BKT_NODES);
    int nvec = nvalid * CAP / 4;               // uint4 count
    uint4* gdst = (uint4*)&ell[(size_t)node0 * CAP];
    const uint4* lsrc = (const uint4*)lell;
    for (int i = tid; i < nvec; i += 256) gdst[i] = lsrc[i];   // dense coalesced
}

// ---- W prep: Wt[n][k] = bf16(W[k][n]), both 128x128 weights in one launch ----
__global__ void k_prepw(const float* __restrict__ W1, const float* __restrict__ W2,
                        ushort* __restrict__ wt1, ushort* __restrict__ wt2) {
    int b = blockIdx.x;
    const float* W = (b < 64) ? W1 : W2;
    ushort* Wt = (b < 64) ? wt1 : wt2;
    int i = (b & 63) * 256 + threadIdx.x;   // 16384 per weight
    int k = i >> 7, n = i & 127;
    Wt[n * 128 + k] = f2bf(W[i]);
}

static __device__ __forceinline__ float combo_dinv(ull cb) {
    return rsqrtf(1.0f + (float)(uint)(cb >> 32) * DGS);
}

// ---- MFMA GEMM: C[M x 128](bf16) = dinv ⊙ (A[M x 128] @ W) ; A fp32 or bf16 ----
__global__ __launch_bounds__(256) void k_gemm_mfma(const void* __restrict__ Ain, int abf,
                                                   const ushort* __restrict__ Wt,
                                                   const ull* __restrict__ combo,
                                                   ushort* __restrict__ C, int M) {
    int wave = threadIdx.x >> 6;
    int lane = threadIdx.x & 63;
    int quad = lane >> 4;
    int mcol = lane & 15;
    int r0 = blockIdx.x * 64 + wave * 16;
    int arow = r0 + mcol;
    if (arow >= M) arow = M - 1;
    floatx4 acc[8];
#pragma unroll
    for (int t = 0; t < 8; t++) acc[t] = (floatx4){0.0f, 0.0f, 0.0f, 0.0f};

    const ushort* Ab = (const ushort*)Ain;
    const float*  Af = (const float*)Ain;
#pragma unroll
    for (int kk = 0; kk < 4; kk++) {
        int koff = kk * 32 + quad * 8;
        short8 a;
        if (abf) {
            a = *(const short8*)&Ab[(size_t)arow * 128 + koff];
        } else {
            const float* ap = &Af[(size_t)arow * 128 + koff];
            float4 x0 = *(const float4*)ap;
            float4 x1 = *(const float4*)(ap + 4);
            union { short8 v; ushort u[8]; } ua;
            ua.u[0] = f2bf(x0.x); ua.u[1] = f2bf(x0.y); ua.u[2] = f2bf(x0.z); ua.u[3] = f2bf(x0.w);
            ua.u[4] = f2bf(x1.x); ua.u[5] = f2bf(x1.y); ua.u[6] = f2bf(x1.z); ua.u[7] = f2bf(x1.w);
            a = ua.v;
        }
#pragma unroll
        for (int t = 0; t < 8; t++) {
            short8 b = *(const short8*)&Wt[(size_t)(t * 16 + mcol) * 128 + koff];
            acc[t] = __builtin_amdgcn_mfma_f32_16x16x32_bf16(a, b, acc[t], 0, 0, 0);
        }
    }
#pragma unroll
    for (int reg = 0; reg < 4; reg++) {
        int row = r0 + quad * 4 + reg;
        if (row < M) {
            float di = combo_dinv(combo[row]);
            ushort* cp = &C[(size_t)row * 128];
#pragma unroll
            for (int t = 0; t < 8; t++) cp[t * 16 + mcol] = f2bf(di * acc[t][reg]);
        }
    }
}

// ---- GEMM3: z'[M x 10](fp32) = dinv ⊙ (A[M x 128](bf16) @ W3[128 x 10]) ----
__global__ __launch_bounds__(256) void k_gemm10(const ushort* __restrict__ A,
                                                const float* __restrict__ W3,
                                                const ull* __restrict__ combo,
                                                float* __restrict__ C3, int M) {
    __shared__ float Ws[1280];
    int tid = threadIdx.x;
    for (int i = tid; i < 1280; i += 256) Ws[i] = W3[i];
    __syncthreads();
    int col = tid & 15;
    int rloc = tid >> 4;
    int row = blockIdx.x * 16 + rloc;
    if (row >= M || col >= 10) return;
    ull cb = combo[row];
    const ushort* a = &A[(size_t)row * 128];
    float acc = 0.0f;
#pragma unroll
    for (int k = 0; k < 128; k += 4) {
        ushort4 av = *(const ushort4*)&a[k];
        acc += __uint_as_float((uint)av.x << 16) * Ws[(k + 0) * 10 + col];
        acc += __uint_as_float((uint)av.y << 16) * Ws[(k + 1) * 10 + col];
        acc += __uint_as_float((uint)av.z << 16) * Ws[(k + 2) * 10 + col];
        acc += __uint_as_float((uint)av.w << 16) * Ws[(k + 3) * 10 + col];
    }
    C3[(size_t)row * 10 + col] = combo_dinv(cb) * acc;
}

// ---- ELL gather, 4-rows-per-instruction layout ----
__global__ __launch_bounds__(256) void k_gather128(const ull* __restrict__ combo,
                                                   const uint* __restrict__ ell,
                                                   const ushort* __restrict__ h,
                                                   const float* __restrict__ b,
                                                   ushort* __restrict__ outp) {
    int node = blockIdx.x * 4 + (threadIdx.x >> 6);
    int lane = threadIdx.x & 63;
    if (node >= NN) return;
    ull cb = combo[node];                          // one 8B broadcast: cnt + deg
    int n = min((int)(uint)cb, 63);                // keep self-slot n within 64 lanes
    float dg = (float)(uint)(cb >> 32) * DGS;
    int ce; float we;
    if (lane < n) {
        uint rec = ell[(size_t)node * CAP + lane];
        ce = (int)(rec & 0xffffu);
        we = (float)(rec >> 16) * EWS;
    } else {
        ce = node;
        we = (lane == n) ? 1.0f : 0.0f;
    }
    int grp  = lane >> 4;     // row-group 0..3
    int col8 = lane & 15;     // 8-col slice
    float acc[8];
#pragma unroll
    for (int f = 0; f < 8; f++) acc[f] = 0.0f;
    int nb = (n + 4) >> 2;    // ceil((n+1)/4) batches, all full (padded)
    for (int bi = 0; bi < nb; bi++) {
        int idx = (bi << 2) | grp;
        int s = __shfl(ce, idx);
        float w = __shfl(we, idx);
        uint4 p = *(const uint4*)&h[(size_t)s * 128 + col8 * 8];
        acc[0] += w * __uint_as_float(p.x << 16);
        acc[1] += w * __uint_as_float(p.x & 0xffff0000u);
        acc[2] += w * __uint_as_float(p.y << 16);
        acc[3] += w * __uint_as_float(p.y & 0xffff0000u);
        acc[4] += w * __uint_as_float(p.z << 16);
        acc[5] += w * __uint_as_float(p.z & 0xffff0000u);
        acc[6] += w * __uint_as_float(p.w << 16);
        acc[7] += w * __uint_as_float(p.w & 0xffff0000u);
    }
#pragma unroll
    for (int f = 0; f < 8; f++) {
        acc[f] += __shfl_xor(acc[f], 16);
        acc[f] += __shfl_xor(acc[f], 32);
    }
    if (lane < 16) {
        float di = rsqrtf(1.0f + dg);
        union { ushort u[8]; uint4 v; } o;
#pragma unroll
        for (int f = 0; f < 8; f++) {
            float vv = fmaxf(di * acc[f] + b[col8 * 8 + f], 0.0f);
            o.u[f] = f2bf(vv);
        }
        *(uint4*)&outp[(size_t)node * 128 + col8 * 8] = o.v;
    }
}

// ---- pool stage 1, 4-row-group layout (r8: was 43us, instr-bound: 640 scalar ----
// ---- loads + 60 shfls/node). Now: per 4-record batch each lane does 2 shfl + ----
// ---- 1 coalesced 4B load + 1 fma; wave reduce = 2 shfl_xor; 10 parallel LDS ----
// ---- atomics. ~25 instrs/node vs ~80. agg3[d]=dinv_d*(sum ew*z'[s]+z'[d]).  ----
__global__ __launch_bounds__(256) void k_pool_node(const ull* __restrict__ combo,
                                                   const uint* __restrict__ ell,
                                                   const float* __restrict__ z,
                                                   const int* __restrict__ batch,
                                                   float* __restrict__ partial) {
    __shared__ float ls[NG * CO + NG];
    for (int i = threadIdx.x; i < NG * CO + NG; i += 256) ls[i] = 0.0f;
    __syncthreads();
    int lane = threadIdx.x & 63;
    int grp  = lane >> 4;     // record-group 0..3
    int c    = lane & 15;     // col slice; cols 0..9 valid
    int gwave = blockIdx.x * 4 + (threadIdx.x >> 6);
    for (int node = gwave; node < NN; node += NB * 4) {
        ull cb = combo[node];
        int n = min((int)(uint)cb, 63);           // self-slot at lane n
        int ce; float we;
        if (lane < n) {
            uint rec = ell[(size_t)node * CAP + lane];
            ce = (int)(rec & 0xffffu);
            we = (float)(rec >> 16) * EWS;
        } else {
            ce = node;
            we = (lane == n) ? 1.0f : 0.0f;       // self term z'[d]; pad w=0
        }
        float acc = 0.0f;
        int nb = (n + 4) >> 2;                    // ceil((n+1)/4) batches
        for (int bi = 0; bi < nb; bi++) {
            int idx = (bi << 2) | grp;
            int s = __shfl(ce, idx);
            float w = __shfl(we, idx);
            float v = (c < 10) ? z[(size_t)s * 10 + c] : 0.0f;
            acc += w * v;
        }
        acc += __shfl_xor(acc, 16);
        acc += __shfl_xor(acc, 32);
        int g = batch[node];                      // broadcast load
        if (lane < 10) {
            float di = combo_dinv(cb);
            atomicAdd(&ls[g * 10 + lane], di * acc);
        } else if (lane == 10) {
            atomicAdd(&ls[NG * CO + g], 1.0f);
        }
    }
    __syncthreads();
    float* pb = &partial[(size_t)blockIdx.x * (NG * CO + NG)];
    for (int i = threadIdx.x; i < NG * CO + NG; i += 256) pb[i] = ls[i];
}

// ---- pool stage 2 + log_softmax: one block (256 thr) per graph ----
__global__ __launch_bounds__(256) void k_pool_final(const float* __restrict__ partial,
                                                    const float* __restrict__ b3,
                                                    float* __restrict__ out) {
    __shared__ float red[4][11];
    int g = blockIdx.x;
    int t = threadIdx.x;
    int lane = t & 63, wv = t >> 6;
    float v[10]; float c = 0.0f;
#pragma unroll
    for (int f = 0; f < 10; f++) v[f] = 0.0f;
    for (int b = t; b < NB; b += 256) {
        const float* pb = &partial[(size_t)b * (NG * CO + NG)];
#pragma unroll
        for (int f = 0; f < 10; f++) v[f] += pb[g * 10 + f];
        c += pb[NG * CO + g];
    }
#pragma unroll
    for (int off = 32; off; off >>= 1) {
#pragma unroll
        for (int f = 0; f < 10; f++) v[f] += __shfl_down(v[f], off);
        c += __shfl_down(c, off);
    }
    if (lane == 0) {
#pragma unroll
        for (int f = 0; f < 10; f++) red[wv][f] = v[f];
        red[wv][10] = c;
    }
    __syncthreads();
    if (t == 0) {
        float p[10], m = -1e30f;
        float cc = red[0][10] + red[1][10] + red[2][10] + red[3][10];
        cc = fmaxf(cc, 1.0f);
#pragma unroll
        for (int f = 0; f < 10; f++) {
            p[f] = (red[0][f] + red[1][f] + red[2][f] + red[3][f]) / cc + b3[f];
            m = fmaxf(m, p[f]);
        }
        float ssum = 0.0f;
#pragma unroll
        for (int f = 0; f < 10; f++) ssum += __expf(p[f] - m);
        float lse = m + __logf(ssum);
#pragma unroll
        for (int f = 0; f < 10; f++) out[g * 10 + f] = p[f] - lse;
    }
}

extern "C" void kernel_launch(void* const* d_in, const int* in_sizes, int n_in,
                              void* d_out, int out_size, void* d_ws, size_t ws_size,
                              hipStream_t stream) {
    const float* x     = (const float*)d_in[0];
    const int*   ei    = (const int*)d_in[1];     // [2, E]
    const float* ea    = (const float*)d_in[2];
    const int*   batch = (const int*)d_in[3];
    const float* W1    = (const float*)d_in[4];
    const float* b1    = (const float*)d_in[5];
    const float* W2    = (const float*)d_in[6];
    const float* b2    = (const float*)d_in[7];
    const float* W3    = (const float*)d_in[8];
    const float* b3    = (const float*)d_in[9];
    float* out = (float*)d_out;
    float* ws  = (float*)d_ws;

    const int* esrc = ei;
    const int* edst = ei + NE;

    // workspace layout (float offsets; all 16B aligned)
    ushort* hb      = (ushort*)ws;                 // N*128 bf16 = 3,200,000 floats
    ushort* gb      = (ushort*)(ws + 3200000);     // N*128 bf16 = 3,200,000 floats
    float*  z       = ws + 6400000;                // 500,000
    ull*    combo   = (ull*)(ws + 6900000);        // NN x u64 (cnt | deg16.16)
    uint*   ell     = (uint*)(ws + 7000000);       // NN*CAP u32 = 3,200,000
    ushort* wt1     = (ushort*)(ws + 10200000);    // 16384 ushorts (bf16 W1^T)
    ushort* wt2     = (ushort*)(ws + 10210000);    // 16384 ushorts (bf16 W2^T)
    float*  partial = (float*)hb;                  // NB*1408 floats, overlays hb (dead then)
    // bucket overlays (dead before their overwriters run):
    ull*    bkt     = (ull*)gb;                    // NBKT*NSEG*SEGCAP*8B = 11.2MB <= gb(12.8MB)
    uint*   bcnt    = (uint*)z;                    // NBKT*NSEG*16 uints = 200KB <= z(2MB)

    // --- ELL build: bucket scatter (XCD-segmented) -> LDS-local ELL assembly ---
    hipMemsetAsync(bcnt, 0, (size_t)NBKT * NSEG * 16 * sizeof(uint), stream);
    k_bucket<<<(NE + 255) / 256, 256, 0, stream>>>(esrc, edst, ea, bcnt, bkt);
    k_ellbuild<<<NBKT, 256, 0, stream>>>(bcnt, bkt, combo, ell);
    k_prepw<<<128, 256, 0, stream>>>(W1, W2, wt1, wt2);

    // --- layer 1: h' = dinv*(X@W1) (MFMA) ; gather -> gb (bf16) ---
    k_gemm_mfma<<<(NN + 63) / 64, 256, 0, stream>>>(x, 0, wt1, combo, hb, NN);
    k_gather128<<<(NN + 3) / 4, 256, 0, stream>>>(combo, ell, hb, b1, gb);

    // --- layer 2 ---
    k_gemm_mfma<<<(NN + 63) / 64, 256, 0, stream>>>(gb, 1, wt2, combo, hb, NN);
    k_gather128<<<(NN + 3) / 4, 256, 0, stream>>>(combo, ell, hb, b2, gb);

    // --- layer 3: z' = dinv*(gb@W3), pool over nodes ---
    k_gemm10<<<(NN + 15) / 16, 256, 0, stream>>>(gb, W3, combo, z, NN);
    k_pool_node<<<NB, 256, 0, stream>>>(combo, ell, z, batch, partial);
    k_pool_final<<<NG, 256, 0, stream>>>(partial, b3, out);
}